// Round 8
// baseline (510.497 us; speedup 1.0000x reference)
//
#include <hip/hip_runtime.h>
#include <hip/hip_bf16.h>

#define NN 100000
#define EE 1600000
#define RR 8
#define NBKT 196          // ceil(NN/512) buckets of 512 nodes
#define ACHUNK 8192       // edges per partition block
#define CAP 10240         // per-bucket capacity: mean 8192, sd ~90 -> 22 sigma headroom
#define NB_NODES ((NN + 63) / 64)   // 1563 node tiles

typedef __attribute__((ext_vector_type(8))) short bf16x8;
typedef __attribute__((ext_vector_type(4))) float f32x4;

__device__ __forceinline__ unsigned short f2bf(float v) {
    __hip_bfloat16 h = __float2bfloat16(v);
    return *reinterpret_cast<unsigned short*>(&h);
}
__device__ __forceinline__ float bf2f(unsigned short u) {
    unsigned x = (unsigned)u << 16;
    return __uint_as_float(x);
}

// ---------- prep device helpers ----------
template<int IN_DIM>
__device__ __forceinline__ void wt_frag_dev(const float* __restrict__ W,
                                            unsigned short* __restrict__ Wf, int r) {
    constexpr int KSTEPS = IN_DIM / 32;
    for (int i = threadIdx.x; i < IN_DIM * 64; i += 256) {
        int k = i >> 6, o = i & 63;
        int ks = k >> 5, quad = (k >> 3) & 3, j = k & 7;
        int tl = o >> 4, l16 = o & 15;
        int lane = quad * 16 + l16;
        size_t idx = ((((size_t)r * KSTEPS + ks) * 4 + tl) * 64 + lane) * 8 + j;
        Wf[idx] = f2bf(W[((size_t)r * IN_DIM + k) * 64 + o]);
    }
}

template<int IN_DIM>
__device__ __forceinline__ void wqk_frag_dev(const float* __restrict__ W,
        const float* __restrict__ q, const float* __restrict__ k,
        unsigned short* __restrict__ Sf, int blk, int nb) {
    for (int i = blk * 256 + threadIdx.x; i < IN_DIM * 16; i += nb * 256) {
        int j = i & 7, lane = (i >> 3) & 63, ks = i >> 9;
        int col = lane & 15, quad = lane >> 4;
        int kd = ks * 32 + quad * 8 + j;
        const float* v = (col < 8) ? q : k;
        int r = (col < 8) ? col : col - 8;
        float s = 0.f;
        #pragma unroll
        for (int o = 0; o < 64; o++) s += W[((size_t)r * IN_DIM + kd) * 64 + o] * v[o];
        Sf[i] = f2bf(s);
    }
}

// one kernel: all weight prep + all zero-init
__global__ __launch_bounds__(256)
void prep(const float* __restrict__ W1, const float* __restrict__ q1, const float* __restrict__ k1,
          const float* __restrict__ W2, const float* __restrict__ q2, const float* __restrict__ k2,
          unsigned short* __restrict__ Wf1, unsigned short* __restrict__ Wf2,
          unsigned short* __restrict__ Sf1, unsigned short* __restrict__ Sf2,
          unsigned* __restrict__ bcnt, float* __restrict__ stats)
{
    int b = blockIdx.x;
    if (b < 8)        wt_frag_dev<128>(W1, Wf1, b);
    else if (b < 16)  wt_frag_dev<64>(W2, Wf2, b - 8);
    else if (b < 20)  wqk_frag_dev<128>(W1, q1, k1, Sf1, b - 16, 4);
    else if (b == 20) wqk_frag_dev<64>(W2, q2, k2, Sf2, 0, 1);
    else {
        int t = threadIdx.x;
        if (t < NBKT) bcnt[t] = 0;
        if (t < 128) stats[t] = 0.f;
    }
}

// ---------------- bucketed CSR build (single-pass: fixed-capacity buckets) ----------------
__global__ __launch_bounds__(256)
void part_scatter(const int* __restrict__ src, const int* __restrict__ dst,
                  const int* __restrict__ et, unsigned* __restrict__ bcnt,
                  unsigned* __restrict__ tmp) {
    __shared__ unsigned h[NBKT], base[NBKT];
    int t = threadIdx.x;
    for (int i = t; i < NBKT; i += 256) h[i] = 0;
    __syncthreads();
    int e0 = blockIdx.x * ACHUNK;
    for (int i = t; i < ACHUNK; i += 256) {
        int e = e0 + i;
        if (e < EE) atomicAdd(&h[((unsigned)dst[e]) >> 9], 1u);
    }
    __syncthreads();
    for (int i = t; i < NBKT; i += 256) {
        base[i] = (unsigned)i * CAP + (h[i] ? atomicAdd(&bcnt[i], h[i]) : 0u);
        h[i] = 0;
    }
    __syncthreads();
    for (int i = t; i < ACHUNK; i += 256) {
        int e = e0 + i;
        if (e < EE) {
            unsigned d = (unsigned)dst[e];
            unsigned bk = d >> 9;
            unsigned off = atomicAdd(&h[bk], 1u);
            unsigned pos = base[bk] + off;
            if (pos < (bk + 1u) * CAP) {   // statistically unreachable clamp
                unsigned val = ((d & 511u) << 23) | ((unsigned)et[e] << 20) | (unsigned)src[e];
                tmp[pos] = val;
            }
        }
    }
}

__global__ __launch_bounds__(512)
void bucket_csr(const unsigned* __restrict__ bcnt, const unsigned* __restrict__ tmp,
                unsigned* __restrict__ rowstart, unsigned* __restrict__ rowdeg,
                unsigned* __restrict__ pk) {
    __shared__ unsigned lcnt[512], lscan[512], lrs[512];
    int b = blockIdx.x, t = threadIdx.x;
    unsigned ebeg = (unsigned)b * CAP;
    unsigned cnt = min(bcnt[b], (unsigned)CAP);
    unsigned eend = ebeg + cnt;
    lcnt[t] = 0;
    __syncthreads();
    for (unsigned i = ebeg + t; i < eend; i += 512)
        atomicAdd(&lcnt[tmp[i] >> 23], 1u);
    __syncthreads();
    unsigned v = lcnt[t];
    lscan[t] = v;
    __syncthreads();
    for (int off = 1; off < 512; off <<= 1) {
        unsigned u = (t >= off) ? lscan[t - off] : 0u;
        __syncthreads();
        lscan[t] += u;
        __syncthreads();
    }
    unsigned excl = lscan[t] - v;
    lrs[t] = ebeg + excl;
    int node = b * 512 + t;
    if (node < NN) { rowstart[node] = ebeg + excl; rowdeg[node] = v; }
    lcnt[t] = 0;
    __syncthreads();
    for (unsigned i = ebeg + t; i < eend; i += 512) {
        unsigned val = tmp[i];
        unsigned d = val >> 23;
        unsigned pos = lrs[d] + atomicAdd(&lcnt[d], 1u);
        pk[pos] = val & 0x7FFFFFu;
    }
}

// ---------- MFMA GEMM, grid-parallel over relations ----------
// R3-R7 evidence: the serial 8-relation loop is latency-bound at 84% idle
// REGARDLESS of staging scheme (69/61/55/68us). Restructure: grid (9, NB_NODES);
// slot 0..7 = one relation's 64-row GEMM, slot 8 = score GEMM (sq/sk+gmax).
// One barrier per block, no inner loop; 14067 blocks give the scheduler TLP
// to hide all latencies. x re-staged 9x (L2/L3-hot), weights 16KB L2-hot.
template<int IN_DIM, bool BF16IN>
__global__ __launch_bounds__(256)
void gemm_mfma(const void* __restrict__ xv, const unsigned short* __restrict__ Wf,
               const unsigned short* __restrict__ Sf,
               unsigned short* __restrict__ xw,
               float* __restrict__ sq, float* __restrict__ sk,
               float* __restrict__ gmax)
{
    constexpr int KSTEPS = IN_DIM / 32;
    constexpr int NB = IN_DIM / 8;
    constexpr int WITEMS = KSTEPS * 4 * 64;           // bf16x8 items per relation
    __shared__ alignas(16) unsigned short xl[64 * IN_DIM];   // 16KB (128) / 8KB (64)
    __shared__ alignas(16) unsigned short wl[WITEMS * 8];    // 16KB (128) / 8KB (64)
    __shared__ float smax[4][8];

    const int slot = blockIdx.x;                      // 0..7 relation, 8 = scores
    const int n0 = blockIdx.y * 64;
    const int t = threadIdx.x;
    const int wave = t >> 6, lane = t & 63;
    const int quad = lane >> 4, l16 = lane & 15;

    // stage x tile (+ this slot's weights) — one barrier covers both
    for (int c = t; c < 64 * IN_DIM / 4; c += 256) {
        int row = c / (IN_DIM / 4), kc = (c % (IN_DIM / 4)) * 4;
        int gr = n0 + row;
        ushort4 u = make_ushort4(0, 0, 0, 0);
        if constexpr (BF16IN) {
            if (gr < NN) u = *(const ushort4*)((const unsigned short*)xv + (size_t)gr * IN_DIM + kc);
        } else {
            if (gr < NN) {
                float4 v = *(const float4*)((const float*)xv + (size_t)gr * IN_DIM + kc);
                u.x = f2bf(v.x); u.y = f2bf(v.y); u.z = f2bf(v.z); u.w = f2bf(v.w);
            }
        }
        int b = kc >> 3;
        *(ushort4*)&xl[row * IN_DIM + ((b ^ (row & (NB - 1))) << 3) + (kc & 7)] = u;
    }
    if (slot < 8) {
        const unsigned short* Wr = Wf + (size_t)slot * WITEMS * 8;
        #pragma unroll
        for (int i = t; i < WITEMS; i += 256)
            *(bf16x8*)&wl[(size_t)i * 8] = *(const bf16x8*)(Wr + (size_t)i * 8);
    }
    __syncthreads();

    bf16x8 afr[KSTEPS];
    const int arow = wave * 16 + l16;
    #pragma unroll
    for (int ks = 0; ks < KSTEPS; ks++) {
        int b = ks * 4 + quad;
        afr[ks] = *(const bf16x8*)&xl[arow * IN_DIM + ((b ^ (arow & (NB - 1))) << 3)];
    }

    if (slot == 8) {
        // ---- sq/sk for ALL relations via one MFMA chain + per-block sk max ----
        f32x4 accs = {0.f, 0.f, 0.f, 0.f};
        #pragma unroll
        for (int ks = 0; ks < KSTEPS; ks++) {
            bf16x8 sfr = *(const bf16x8*)&Sf[(ks * 64 + lane) * 8];
            accs = __builtin_amdgcn_mfma_f32_16x16x32_bf16(afr[ks], sfr, accs, 0, 0, 0);
        }
        float pm = -1e30f;
        #pragma unroll
        for (int reg = 0; reg < 4; reg++) {
            int grow = n0 + wave * 16 + quad * 4 + reg;
            if (grow < NN) {
                if (l16 < 8) sq[(size_t)l16 * NN + grow] = accs[reg];
                else { sk[(size_t)(l16 - 8) * NN + grow] = accs[reg]; pm = fmaxf(pm, accs[reg]); }
            }
        }
        pm = fmaxf(pm, __shfl_xor(pm, 16, 64));
        pm = fmaxf(pm, __shfl_xor(pm, 32, 64));
        if (quad == 0 && l16 >= 8) smax[wave][l16 - 8] = pm;
        __syncthreads();
        if (t < 8) {
            float v = fmaxf(fmaxf(smax[0][t], smax[1][t]), fmaxf(smax[2][t], smax[3][t]));
            gmax[blockIdx.y * 8 + t] = v;             // plain store, no RMW
        }
        return;
    }

    // ---- one relation's 64xIN_DIM x IN_DIMx64 GEMM ----
    bf16x8 bfr[KSTEPS][4];
    #pragma unroll
    for (int ks = 0; ks < KSTEPS; ks++)
        #pragma unroll
        for (int tl = 0; tl < 4; tl++)
            bfr[ks][tl] = *(const bf16x8*)&wl[(size_t)((ks * 4 + tl) * 64 + lane) * 8];

    f32x4 acc[4] = {{0.f,0.f,0.f,0.f},{0.f,0.f,0.f,0.f},{0.f,0.f,0.f,0.f},{0.f,0.f,0.f,0.f}};
    #pragma unroll
    for (int ks = 0; ks < KSTEPS; ks++)
        #pragma unroll
        for (int tl = 0; tl < 4; tl++)
            acc[tl] = __builtin_amdgcn_mfma_f32_16x16x32_bf16(afr[ks], bfr[ks][tl], acc[tl], 0, 0, 0);

    const size_t rbase = (size_t)slot * NN;
    #pragma unroll
    for (int reg = 0; reg < 4; reg++) {
        int grow = n0 + wave * 16 + quad * 4 + reg;
        if (grow < NN) {
            ushort4 u;
            u.x = f2bf(acc[0][reg]); u.y = f2bf(acc[1][reg]);
            u.z = f2bf(acc[2][reg]); u.w = f2bf(acc[3][reg]);
            *(ushort4*)(xw + (rbase + grow) * 64 + l16 * 4) = u;
        }
    }
}

// ---------- parallel tree-reduce: gmax[1563][8] -> mxk[8] (R5-proven) ----------
__global__ __launch_bounds__(256)
void max_reduce(const float* __restrict__ gmax, float* __restrict__ mxk) {
    __shared__ float smr[32][8];
    int t = threadIdx.x;
    int r = t & 7, grp = t >> 3;                      // 32 groups of 8
    float m0 = -1e30f, m1 = -1e30f, m2 = -1e30f, m3 = -1e30f;
    for (int i = grp; i < NB_NODES; i += 128) {
        m0 = fmaxf(m0, gmax[i * 8 + r]);
        int i1 = i + 32, i2 = i + 64, i3 = i + 96;
        if (i1 < NB_NODES) m1 = fmaxf(m1, gmax[i1 * 8 + r]);
        if (i2 < NB_NODES) m2 = fmaxf(m2, gmax[i2 * 8 + r]);
        if (i3 < NB_NODES) m3 = fmaxf(m3, gmax[i3 * 8 + r]);
    }
    smr[grp][r] = fmaxf(fmaxf(m0, m1), fmaxf(m2, m3));
    __syncthreads();
    if (t < 8) {
        float mm = smr[0][t];
        #pragma unroll
        for (int g2 = 1; g2 < 32; g2++) mm = fmaxf(mm, smr[g2][t]);
        mxk[t] = mm;
    }
}

// ---------- Fused per-node softmax + aggregate (R5-proven form, 59.2us) ----------
// 4 groups of 16 lanes, 8 edges / 2 independent 8B gathers in flight.
// R6's 16B restructure measured SLOWER (61.2) -> reverted. The gather is at the
// random-access BW ceiling (~3.1 TB/s); treat as floor.
template<int LAYER>
__global__ __launch_bounds__(256)
void node_aggregate(const unsigned* __restrict__ rowstart, const unsigned* __restrict__ rowdeg,
                    const unsigned* __restrict__ pk,
                    const float* __restrict__ sq, const float* __restrict__ sk,
                    const float* __restrict__ mxk,
                    const unsigned short* __restrict__ xw, const float* __restrict__ b,
                    void* __restrict__ outv)
{
    const int node = blockIdx.x * 4 + (threadIdx.x >> 6);
    const int lane = threadIdx.x & 63;
    const int g = lane >> 4, c16 = lane & 15;
    const unsigned beg = rowstart[node];
    const unsigned deg = rowdeg[node];
    const unsigned end = beg + deg;

    const float sqreg = sq[(size_t)(lane & 7) * NN + node];
    float tmx = sqreg + mxk[lane & 7];
    tmx = fmaxf(tmx, __shfl_xor(tmx, 1, 64));
    tmx = fmaxf(tmx, __shfl_xor(tmx, 2, 64));
    tmx = fmaxf(tmx, __shfl_xor(tmx, 4, 64));
    const float m = tmx > 0.f ? tmx : 0.2f * tmx;   // leaky is monotonic: bound survives

    float a0 = 0.f, a1 = 0.f, a2 = 0.f, a3 = 0.f, den = 0.f;
    for (unsigned c0 = beg; c0 < end; c0 += 64) {
        unsigned i = c0 + lane;
        unsigned p = 0;
        if (i < end) p = pk[i];
        unsigned r = p >> 20;
        unsigned rowidx = r * NN + (p & 0xFFFFFu);   // pads -> row 0 (harmless)
        float skv = sk[rowidx];
        float sqv_e = __shfl(sqreg, (int)r, 64);     // uniform flow: sources active
        float a = sqv_e + skv;
        a = a > 0.f ? a : 0.2f * a;
        float w = __expf(a - m);
        if (i >= end) w = 0.f;
        den += w;
        int cnt8 = ((int)min(64u, end - c0) + 7) & ~7;   // pad lanes have w=0
        for (int j = 0; j < cnt8; j += 8) {
            float    w0 = __shfl(w, j + g, 64);
            unsigned r0 = (unsigned)__shfl((int)rowidx, j + g, 64);
            float    w1 = __shfl(w, j + 4 + g, 64);
            unsigned r1 = (unsigned)__shfl((int)rowidx, j + 4 + g, 64);
            ushort4 v0 = *(const ushort4*)(xw + (size_t)r0 * 64 + c16 * 4);
            ushort4 v1 = *(const ushort4*)(xw + (size_t)r1 * 64 + c16 * 4);
            a0 += w0 * bf2f(v0.x) + w1 * bf2f(v1.x);
            a1 += w0 * bf2f(v0.y) + w1 * bf2f(v1.y);
            a2 += w0 * bf2f(v0.z) + w1 * bf2f(v1.z);
            a3 += w0 * bf2f(v0.w) + w1 * bf2f(v1.w);
        }
    }
    #pragma unroll
    for (int off = 32; off >= 1; off >>= 1)
        den += __shfl_xor(den, off, 64);
    // combine the 4 edge-subgroups: lanes L, L^16, L^32, L^48 hold same channels
    a0 += __shfl_xor(a0, 16, 64); a0 += __shfl_xor(a0, 32, 64);
    a1 += __shfl_xor(a1, 16, 64); a1 += __shfl_xor(a1, 32, 64);
    a2 += __shfl_xor(a2, 16, 64); a2 += __shfl_xor(a2, 32, 64);
    a3 += __shfl_xor(a3, 16, 64); a3 += __shfl_xor(a3, 32, 64);

    float accg = (g == 0) ? a0 : (g == 1) ? a1 : (g == 2) ? a2 : a3;
    float res = (deg > 0) ? accg / (den + 1e-16f) : 0.f;
    int c = g * 16 + c16;
    if constexpr (LAYER == 1) {
        res += b[c];
        res = res > 0.f ? res : 0.f;
        ((unsigned short*)outv)[(size_t)node * 64 + c] = f2bf(res);
    } else {
        ((float*)outv)[(size_t)node * 64 + c] = res;
    }
}

// ---------------- BatchNorm (separate stats kernel: 512 blocks -> 65k atomics, R0-proven) ----
__global__ __launch_bounds__(256)
void bn_stats(const float* __restrict__ x, float* __restrict__ stats)
{
    int c = threadIdx.x & 63;
    int w = threadIdx.x >> 6;
    float s = 0.f, s2 = 0.f;
    for (int row = blockIdx.x * 4 + w; row < NN; row += gridDim.x * 4) {
        float v = x[(size_t)row * 64 + c];
        s += v; s2 += v * v;
    }
    __shared__ float ls[4][64], ls2[4][64];
    ls[w][c] = s; ls2[w][c] = s2;
    __syncthreads();
    if (threadIdx.x < 64) {
        atomicAdd(&stats[c],      ls[0][c] + ls[1][c] + ls[2][c] + ls[3][c]);
        atomicAdd(&stats[64 + c], ls2[0][c] + ls2[1][c] + ls2[2][c] + ls2[3][c]);
    }
}

__global__ __launch_bounds__(256)
void bn_apply(float* __restrict__ x, const float* __restrict__ stats,
              const float* __restrict__ gamma, const float* __restrict__ beta)
{
    int i = blockIdx.x * 256 + threadIdx.x;
    if (i >= NN * 64) return;
    int c = i & 63;
    float mean = stats[c] * (1.f / NN);
    float var  = stats[64 + c] * (1.f / NN) - mean * mean;
    float sc   = rsqrtf(var + 1e-5f) * gamma[c];
    float v = (x[i] - mean) * sc + beta[c];
    x[i] = v > 0.f ? v : 0.01f * v;
}

// ---------------- driver ----------------
extern "C" void kernel_launch(void* const* d_in, const int* in_sizes, int n_in,
                              void* d_out, int out_size, void* d_ws, size_t ws_size,
                              hipStream_t stream)
{
    const float* x0 = (const float*)d_in[0];
    const int*   ei = (const int*)d_in[1];
    const int*   et = (const int*)d_in[2];
    const float* W1 = (const float*)d_in[3];
    const float* q1 = (const float*)d_in[4];
    const float* k1 = (const float*)d_in[5];
    const float* b1 = (const float*)d_in[6];
    const float* W2 = (const float*)d_in[7];
    const float* q2 = (const float*)d_in[8];
    const float* k2 = (const float*)d_in[9];
    const float* gamma = (const float*)d_in[11];
    const float* beta  = (const float*)d_in[12];
    const int* src = ei;
    const int* dst = ei + EE;
    float* out = (float*)d_out;

    char* base = (char*)d_ws;
    size_t off = 0;
    auto take = [&](size_t bytes) -> char* {
        char* p = base + off;
        off = (off + bytes + 255) & ~(size_t)255;
        return p;
    };
    float*    sq       = (float*)take((size_t)RR * NN * 4);
    float*    sk       = (float*)take((size_t)RR * NN * 4);
    unsigned* rowstart = (unsigned*)take((size_t)NN * 4);
    unsigned* rowdeg   = (unsigned*)take((size_t)NN * 4);
    unsigned* bcnt     = (unsigned*)take((size_t)NBKT * 4);
    unsigned* tmp      = (unsigned*)take((size_t)NBKT * CAP * 4);
    unsigned* pk       = (unsigned*)take((size_t)NBKT * CAP * 4);
    unsigned short* x1 = (unsigned short*)take((size_t)NN * 64 * 2);
    float*    stats    = (float*)take(512);
    float*    gmax     = (float*)take((size_t)NB_NODES * 8 * 4);
    float*    mxk1     = (float*)take(RR * 4);
    float*    mxk2     = (float*)take(RR * 4);
    unsigned short* Wf1 = (unsigned short*)take((size_t)RR * 128 * 64 * 2);
    unsigned short* Wf2 = (unsigned short*)take((size_t)RR * 64 * 64 * 2);
    unsigned short* Sf1 = (unsigned short*)take((size_t)128 * 16 * 2);
    unsigned short* Sf2 = (unsigned short*)take((size_t)64 * 16 * 2);
    unsigned short* xw  = (unsigned short*)take((size_t)RR * NN * 64 * 2);

    const int nb_part  = (EE + ACHUNK - 1) / ACHUNK;   // 196
    const int nb_agg   = NN / 4;                       // 25000
    const int nb_elem  = (NN * 64) / 256;

    prep<<<22, 256, 0, stream>>>(W1, q1, k1, W2, q2, k2, Wf1, Wf2, Sf1, Sf2,
                                 bcnt, stats);
    part_scatter<<<nb_part, 256, 0, stream>>>(src, dst, et, bcnt, tmp);
    bucket_csr<<<NBKT, 512, 0, stream>>>(bcnt, tmp, rowstart, rowdeg, pk);

    gemm_mfma<128, false><<<dim3(9, NB_NODES), 256, 0, stream>>>(x0, Wf1, Sf1, xw, sq, sk, gmax);
    max_reduce<<<1, 256, 0, stream>>>(gmax, mxk1);
    node_aggregate<1><<<nb_agg, 256, 0, stream>>>(rowstart, rowdeg, pk, sq, sk, mxk1,
                                                  xw, b1, x1);

    gemm_mfma<64, true><<<dim3(9, NB_NODES), 256, 0, stream>>>(x1, Wf2, Sf2, xw, sq, sk, gmax);
    max_reduce<<<1, 256, 0, stream>>>(gmax, mxk2);
    node_aggregate<2><<<nb_agg, 256, 0, stream>>>(rowstart, rowdeg, pk, sq, sk, mxk2,
                                                  xw, nullptr, out);

    bn_stats<<<512, 256, 0, stream>>>(out, stats);
    bn_apply<<<nb_elem, 256, 0, stream>>>(out, stats, gamma, beta);
}

// Round 9
// 414.513 us; speedup vs baseline: 1.2316x; 1.2316x over previous
//
#include <hip/hip_runtime.h>
#include <hip/hip_bf16.h>

#define NN 100000
#define EE 1600000
#define RR 8
#define NBKT 391          // ceil(NN/256) buckets of 256 nodes (R9: 2x blocks for TLP)
#define ACHUNK 2048       // edges per partition block (R9: 8192->2048, 782 blocks)
#define CAP 5120          // per-bucket capacity: mean 4096, sd ~64 -> 16 sigma headroom
#define NB_NODES ((NN + 63) / 64)   // 1563 node tiles

typedef __attribute__((ext_vector_type(8))) short bf16x8;
typedef __attribute__((ext_vector_type(4))) float f32x4;

__device__ __forceinline__ unsigned short f2bf(float v) {
    __hip_bfloat16 h = __float2bfloat16(v);
    return *reinterpret_cast<unsigned short*>(&h);
}
__device__ __forceinline__ float bf2f(unsigned short u) {
    unsigned x = (unsigned)u << 16;
    return __uint_as_float(x);
}

// ---------- prep device helpers (R9: sub-block split for TLP) ----------
template<int IN_DIM>
__device__ __forceinline__ void wt_frag_dev(const float* __restrict__ W,
                                            unsigned short* __restrict__ Wf,
                                            int r, int blk, int nb) {
    constexpr int KSTEPS = IN_DIM / 32;
    for (int i = blk * 256 + threadIdx.x; i < IN_DIM * 64; i += nb * 256) {
        int k = i >> 6, o = i & 63;
        int ks = k >> 5, quad = (k >> 3) & 3, j = k & 7;
        int tl = o >> 4, l16 = o & 15;
        int lane = quad * 16 + l16;
        size_t idx = ((((size_t)r * KSTEPS + ks) * 4 + tl) * 64 + lane) * 8 + j;
        Wf[idx] = f2bf(W[((size_t)r * IN_DIM + k) * 64 + o]);
    }
}

template<int IN_DIM>
__device__ __forceinline__ void wqk_frag_dev(const float* __restrict__ W,
        const float* __restrict__ q, const float* __restrict__ k,
        unsigned short* __restrict__ Sf, int blk, int nb) {
    for (int i = blk * 256 + threadIdx.x; i < IN_DIM * 16; i += nb * 256) {
        int j = i & 7, lane = (i >> 3) & 63, ks = i >> 9;
        int col = lane & 15, quad = lane >> 4;
        int kd = ks * 32 + quad * 8 + j;
        const float* v = (col < 8) ? q : k;
        int r = (col < 8) ? col : col - 8;
        float s = 0.f;
        #pragma unroll
        for (int o = 0; o < 64; o++) s += W[((size_t)r * IN_DIM + kd) * 64 + o] * v[o];
        Sf[i] = f2bf(s);
    }
}

// one kernel: all weight prep + all zero-init (53 blocks)
__global__ __launch_bounds__(256)
void prep(const float* __restrict__ W1, const float* __restrict__ q1, const float* __restrict__ k1,
          const float* __restrict__ W2, const float* __restrict__ q2, const float* __restrict__ k2,
          unsigned short* __restrict__ Wf1, unsigned short* __restrict__ Wf2,
          unsigned short* __restrict__ Sf1, unsigned short* __restrict__ Sf2,
          unsigned* __restrict__ bcnt, float* __restrict__ stats)
{
    int b = blockIdx.x;
    if (b < 16)       wt_frag_dev<128>(W1, Wf1, b >> 1, b & 1, 2);
    else if (b < 32)  wt_frag_dev<64>(W2, Wf2, (b - 16) >> 1, b & 1, 2);
    else if (b < 48)  wqk_frag_dev<128>(W1, q1, k1, Sf1, b - 32, 16);
    else if (b < 52)  wqk_frag_dev<64>(W2, q2, k2, Sf2, b - 48, 4);
    else {
        int t = threadIdx.x;
        for (int i = t; i < NBKT; i += 256) bcnt[i] = 0;
        if (t < 128) stats[t] = 0.f;
    }
}

// ---------------- bucketed CSR build (single-pass: fixed-capacity buckets) ----------------
__global__ __launch_bounds__(256)
void part_scatter(const int* __restrict__ src, const int* __restrict__ dst,
                  const int* __restrict__ et, unsigned* __restrict__ bcnt,
                  unsigned* __restrict__ tmp) {
    __shared__ unsigned h[NBKT], base[NBKT];
    int t = threadIdx.x;
    for (int i = t; i < NBKT; i += 256) h[i] = 0;
    __syncthreads();
    int e0 = blockIdx.x * ACHUNK;
    for (int i = t; i < ACHUNK; i += 256) {
        int e = e0 + i;
        if (e < EE) atomicAdd(&h[((unsigned)dst[e]) >> 8], 1u);
    }
    __syncthreads();
    for (int i = t; i < NBKT; i += 256) {
        base[i] = (unsigned)i * CAP + (h[i] ? atomicAdd(&bcnt[i], h[i]) : 0u);
        h[i] = 0;
    }
    __syncthreads();
    for (int i = t; i < ACHUNK; i += 256) {
        int e = e0 + i;
        if (e < EE) {
            unsigned d = (unsigned)dst[e];
            unsigned bk = d >> 8;
            unsigned off = atomicAdd(&h[bk], 1u);
            unsigned pos = base[bk] + off;
            if (pos < (bk + 1u) * CAP) {   // statistically unreachable clamp (16 sigma)
                unsigned val = ((d & 255u) << 23) | ((unsigned)et[e] << 20) | (unsigned)src[e];
                tmp[pos] = val;
            }
        }
    }
}

__global__ __launch_bounds__(256)
void bucket_csr(const unsigned* __restrict__ bcnt, const unsigned* __restrict__ tmp,
                unsigned* __restrict__ rowstart, unsigned* __restrict__ rowdeg,
                unsigned* __restrict__ pk) {
    __shared__ unsigned lcnt[256], lscan[256], lrs[256];
    int b = blockIdx.x, t = threadIdx.x;
    unsigned ebeg = (unsigned)b * CAP;
    unsigned cnt = min(bcnt[b], (unsigned)CAP);
    unsigned eend = ebeg + cnt;
    lcnt[t] = 0;
    __syncthreads();
    for (unsigned i = ebeg + t; i < eend; i += 256)
        atomicAdd(&lcnt[tmp[i] >> 23], 1u);
    __syncthreads();
    unsigned v = lcnt[t];
    lscan[t] = v;
    __syncthreads();
    for (int off = 1; off < 256; off <<= 1) {
        unsigned u = (t >= off) ? lscan[t - off] : 0u;
        __syncthreads();
        lscan[t] += u;
        __syncthreads();
    }
    unsigned excl = lscan[t] - v;
    lrs[t] = ebeg + excl;
    int node = b * 256 + t;
    if (node < NN) { rowstart[node] = ebeg + excl; rowdeg[node] = v; }
    lcnt[t] = 0;
    __syncthreads();
    for (unsigned i = ebeg + t; i < eend; i += 256) {
        unsigned val = tmp[i];
        unsigned d = val >> 23;
        unsigned pos = lrs[d] + atomicAdd(&lcnt[d], 1u);
        pk[pos] = val & 0x7FFFFFu;
    }
}

// ---------- MFMA GEMM: serial relations, LDS-staged weights, 2 barriers/relation.
// R5/R6-proven best of 5 structural variants (69/61.5/~55/68/133 us):
// dbuf (R7) cut occupancy, grid-parallel relations (R8) blew FETCH 26->201MB.
// Do not restructure again without new counter evidence. ----------
template<int IN_DIM, bool BF16IN>
__global__ __launch_bounds__(256)
void gemm_mfma(const void* __restrict__ xv, const unsigned short* __restrict__ Wf,
               const unsigned short* __restrict__ Sf,
               unsigned short* __restrict__ xw,
               float* __restrict__ sq, float* __restrict__ sk,
               float* __restrict__ gmax)
{
    constexpr int KSTEPS = IN_DIM / 32;
    constexpr int NB = IN_DIM / 8;
    constexpr int WITEMS = KSTEPS * 4 * 64;           // bf16x8 items per relation
    __shared__ alignas(16) unsigned short xl[64 * IN_DIM];
    __shared__ alignas(16) unsigned short wl[WITEMS * 8];   // 16KB (128) / 8KB (64)
    __shared__ float smax[4][8];

    const int n0 = blockIdx.x * 64;
    const int t = threadIdx.x;
    const int wave = t >> 6, lane = t & 63;
    const int quad = lane >> 4, l16 = lane & 15;

    for (int c = t; c < 64 * IN_DIM / 4; c += 256) {
        int row = c / (IN_DIM / 4), kc = (c % (IN_DIM / 4)) * 4;
        int gr = n0 + row;
        ushort4 u = make_ushort4(0, 0, 0, 0);
        if constexpr (BF16IN) {
            if (gr < NN) u = *(const ushort4*)((const unsigned short*)xv + (size_t)gr * IN_DIM + kc);
        } else {
            if (gr < NN) {
                float4 v = *(const float4*)((const float*)xv + (size_t)gr * IN_DIM + kc);
                u.x = f2bf(v.x); u.y = f2bf(v.y); u.z = f2bf(v.z); u.w = f2bf(v.w);
            }
        }
        int b = kc >> 3;
        *(ushort4*)&xl[row * IN_DIM + ((b ^ (row & (NB - 1))) << 3) + (kc & 7)] = u;
    }
    __syncthreads();

    bf16x8 afr[KSTEPS];
    const int arow = wave * 16 + l16;
    #pragma unroll
    for (int ks = 0; ks < KSTEPS; ks++) {
        int b = ks * 4 + quad;
        afr[ks] = *(const bf16x8*)&xl[arow * IN_DIM + ((b ^ (arow & (NB - 1))) << 3)];
    }

    // ---- sq/sk for ALL relations via one MFMA chain + per-block sk max ----
    {
        f32x4 accs = {0.f, 0.f, 0.f, 0.f};
        #pragma unroll
        for (int ks = 0; ks < KSTEPS; ks++) {
            bf16x8 sfr = *(const bf16x8*)&Sf[(ks * 64 + lane) * 8];
            accs = __builtin_amdgcn_mfma_f32_16x16x32_bf16(afr[ks], sfr, accs, 0, 0, 0);
        }
        float pm = -1e30f;
        #pragma unroll
        for (int reg = 0; reg < 4; reg++) {
            int grow = n0 + wave * 16 + quad * 4 + reg;
            if (grow < NN) {
                if (l16 < 8) sq[(size_t)l16 * NN + grow] = accs[reg];
                else { sk[(size_t)(l16 - 8) * NN + grow] = accs[reg]; pm = fmaxf(pm, accs[reg]); }
            }
        }
        pm = fmaxf(pm, __shfl_xor(pm, 16, 64));
        pm = fmaxf(pm, __shfl_xor(pm, 32, 64));
        if (quad == 0 && l16 >= 8) smax[wave][l16 - 8] = pm;
    }
    __syncthreads();
    if (t < 8) {
        float v = fmaxf(fmaxf(smax[0][t], smax[1][t]), fmaxf(smax[2][t], smax[3][t]));
        gmax[blockIdx.x * 8 + t] = v;                 // plain store, no RMW
    }

    #pragma unroll 1
    for (int r = 0; r < RR; r++) {
        // cooperative staging: 256 threads, coalesced 16B loads, deeply pipelined
        const unsigned short* Wr = Wf + (size_t)r * WITEMS * 8;
        #pragma unroll
        for (int i = t; i < WITEMS; i += 256)
            *(bf16x8*)&wl[(size_t)i * 8] = *(const bf16x8*)(Wr + (size_t)i * 8);
        __syncthreads();

        bf16x8 bfr[KSTEPS][4];
        #pragma unroll
        for (int ks = 0; ks < KSTEPS; ks++)
            #pragma unroll
            for (int tl = 0; tl < 4; tl++)
                bfr[ks][tl] = *(const bf16x8*)&wl[(size_t)((ks * 4 + tl) * 64 + lane) * 8];

        f32x4 acc[4] = {{0.f,0.f,0.f,0.f},{0.f,0.f,0.f,0.f},{0.f,0.f,0.f,0.f},{0.f,0.f,0.f,0.f}};
        #pragma unroll
        for (int ks = 0; ks < KSTEPS; ks++)
            #pragma unroll
            for (int tl = 0; tl < 4; tl++)
                acc[tl] = __builtin_amdgcn_mfma_f32_16x16x32_bf16(afr[ks], bfr[ks][tl], acc[tl], 0, 0, 0);

        const size_t rbase = (size_t)r * NN;
        #pragma unroll
        for (int reg = 0; reg < 4; reg++) {
            int grow = n0 + wave * 16 + quad * 4 + reg;
            if (grow < NN) {
                ushort4 u;
                u.x = f2bf(acc[0][reg]); u.y = f2bf(acc[1][reg]);
                u.z = f2bf(acc[2][reg]); u.w = f2bf(acc[3][reg]);
                *(ushort4*)(xw + (rbase + grow) * 64 + l16 * 4) = u;
            }
        }
        __syncthreads();   // wl reads done before next relation's staging
    }
}

// ---------- parallel tree-reduce: gmax[1563][8] -> mxk[8] (R5-proven) ----------
__global__ __launch_bounds__(256)
void max_reduce(const float* __restrict__ gmax, float* __restrict__ mxk) {
    __shared__ float smr[32][8];
    int t = threadIdx.x;
    int r = t & 7, grp = t >> 3;                      // 32 groups of 8
    float m0 = -1e30f, m1 = -1e30f, m2 = -1e30f, m3 = -1e30f;
    for (int i = grp; i < NB_NODES; i += 128) {
        m0 = fmaxf(m0, gmax[i * 8 + r]);
        int i1 = i + 32, i2 = i + 64, i3 = i + 96;
        if (i1 < NB_NODES) m1 = fmaxf(m1, gmax[i1 * 8 + r]);
        if (i2 < NB_NODES) m2 = fmaxf(m2, gmax[i2 * 8 + r]);
        if (i3 < NB_NODES) m3 = fmaxf(m3, gmax[i3 * 8 + r]);
    }
    smr[grp][r] = fmaxf(fmaxf(m0, m1), fmaxf(m2, m3));
    __syncthreads();
    if (t < 8) {
        float mm = smr[0][t];
        #pragma unroll
        for (int g2 = 1; g2 < 32; g2++) mm = fmaxf(mm, smr[g2][t]);
        mxk[t] = mm;
    }
}

// ---------- Fused per-node softmax + aggregate (R5-proven form, 59.2us) ----------
// 4 groups of 16 lanes, 8 edges / 2 independent 8B gathers in flight.
// R6's 16B restructure measured SLOWER (61.2/dispatch) -> 8B form. The gather is
// at the random-access BW ceiling (~3.1 TB/s); treat as floor.
template<int LAYER>
__global__ __launch_bounds__(256)
void node_aggregate(const unsigned* __restrict__ rowstart, const unsigned* __restrict__ rowdeg,
                    const unsigned* __restrict__ pk,
                    const float* __restrict__ sq, const float* __restrict__ sk,
                    const float* __restrict__ mxk,
                    const unsigned short* __restrict__ xw, const float* __restrict__ b,
                    void* __restrict__ outv)
{
    const int node = blockIdx.x * 4 + (threadIdx.x >> 6);
    const int lane = threadIdx.x & 63;
    const int g = lane >> 4, c16 = lane & 15;
    const unsigned beg = rowstart[node];
    const unsigned deg = rowdeg[node];
    const unsigned end = beg + deg;

    const float sqreg = sq[(size_t)(lane & 7) * NN + node];
    float tmx = sqreg + mxk[lane & 7];
    tmx = fmaxf(tmx, __shfl_xor(tmx, 1, 64));
    tmx = fmaxf(tmx, __shfl_xor(tmx, 2, 64));
    tmx = fmaxf(tmx, __shfl_xor(tmx, 4, 64));
    const float m = tmx > 0.f ? tmx : 0.2f * tmx;   // leaky is monotonic: bound survives

    float a0 = 0.f, a1 = 0.f, a2 = 0.f, a3 = 0.f, den = 0.f;
    for (unsigned c0 = beg; c0 < end; c0 += 64) {
        unsigned i = c0 + lane;
        unsigned p = 0;
        if (i < end) p = pk[i];
        unsigned r = p >> 20;
        unsigned rowidx = r * NN + (p & 0xFFFFFu);   // pads -> row 0 (harmless)
        float skv = sk[rowidx];
        float sqv_e = __shfl(sqreg, (int)r, 64);     // uniform flow: sources active
        float a = sqv_e + skv;
        a = a > 0.f ? a : 0.2f * a;
        float w = __expf(a - m);
        if (i >= end) w = 0.f;
        den += w;
        int cnt8 = ((int)min(64u, end - c0) + 7) & ~7;   // pad lanes have w=0
        for (int j = 0; j < cnt8; j += 8) {
            float    w0 = __shfl(w, j + g, 64);
            unsigned r0 = (unsigned)__shfl((int)rowidx, j + g, 64);
            float    w1 = __shfl(w, j + 4 + g, 64);
            unsigned r1 = (unsigned)__shfl((int)rowidx, j + 4 + g, 64);
            ushort4 v0 = *(const ushort4*)(xw + (size_t)r0 * 64 + c16 * 4);
            ushort4 v1 = *(const ushort4*)(xw + (size_t)r1 * 64 + c16 * 4);
            a0 += w0 * bf2f(v0.x) + w1 * bf2f(v1.x);
            a1 += w0 * bf2f(v0.y) + w1 * bf2f(v1.y);
            a2 += w0 * bf2f(v0.z) + w1 * bf2f(v1.z);
            a3 += w0 * bf2f(v0.w) + w1 * bf2f(v1.w);
        }
    }
    #pragma unroll
    for (int off = 32; off >= 1; off >>= 1)
        den += __shfl_xor(den, off, 64);
    // combine the 4 edge-subgroups: lanes L, L^16, L^32, L^48 hold same channels
    a0 += __shfl_xor(a0, 16, 64); a0 += __shfl_xor(a0, 32, 64);
    a1 += __shfl_xor(a1, 16, 64); a1 += __shfl_xor(a1, 32, 64);
    a2 += __shfl_xor(a2, 16, 64); a2 += __shfl_xor(a2, 32, 64);
    a3 += __shfl_xor(a3, 16, 64); a3 += __shfl_xor(a3, 32, 64);

    float accg = (g == 0) ? a0 : (g == 1) ? a1 : (g == 2) ? a2 : a3;
    float res = (deg > 0) ? accg / (den + 1e-16f) : 0.f;
    int c = g * 16 + c16;
    if constexpr (LAYER == 1) {
        res += b[c];
        res = res > 0.f ? res : 0.f;
        ((unsigned short*)outv)[(size_t)node * 64 + c] = f2bf(res);
    } else {
        ((float*)outv)[(size_t)node * 64 + c] = res;
    }
}

// ---------------- BatchNorm (separate stats kernel: 512 blocks -> 65k atomics, R0-proven) ----
__global__ __launch_bounds__(256)
void bn_stats(const float* __restrict__ x, float* __restrict__ stats)
{
    int c = threadIdx.x & 63;
    int w = threadIdx.x >> 6;
    float s = 0.f, s2 = 0.f;
    for (int row = blockIdx.x * 4 + w; row < NN; row += gridDim.x * 4) {
        float v = x[(size_t)row * 64 + c];
        s += v; s2 += v * v;
    }
    __shared__ float ls[4][64], ls2[4][64];
    ls[w][c] = s; ls2[w][c] = s2;
    __syncthreads();
    if (threadIdx.x < 64) {
        atomicAdd(&stats[c],      ls[0][c] + ls[1][c] + ls[2][c] + ls[3][c]);
        atomicAdd(&stats[64 + c], ls2[0][c] + ls2[1][c] + ls2[2][c] + ls2[3][c]);
    }
}

__global__ __launch_bounds__(256)
void bn_apply(float* __restrict__ x, const float* __restrict__ stats,
              const float* __restrict__ gamma, const float* __restrict__ beta)
{
    int i = blockIdx.x * 256 + threadIdx.x;
    if (i >= NN * 64) return;
    int c = i & 63;
    float mean = stats[c] * (1.f / NN);
    float var  = stats[64 + c] * (1.f / NN) - mean * mean;
    float sc   = rsqrtf(var + 1e-5f) * gamma[c];
    float v = (x[i] - mean) * sc + beta[c];
    x[i] = v > 0.f ? v : 0.01f * v;
}

// ---------------- driver ----------------
extern "C" void kernel_launch(void* const* d_in, const int* in_sizes, int n_in,
                              void* d_out, int out_size, void* d_ws, size_t ws_size,
                              hipStream_t stream)
{
    const float* x0 = (const float*)d_in[0];
    const int*   ei = (const int*)d_in[1];
    const int*   et = (const int*)d_in[2];
    const float* W1 = (const float*)d_in[3];
    const float* q1 = (const float*)d_in[4];
    const float* k1 = (const float*)d_in[5];
    const float* b1 = (const float*)d_in[6];
    const float* W2 = (const float*)d_in[7];
    const float* q2 = (const float*)d_in[8];
    const float* k2 = (const float*)d_in[9];
    const float* gamma = (const float*)d_in[11];
    const float* beta  = (const float*)d_in[12];
    const int* src = ei;
    const int* dst = ei + EE;
    float* out = (float*)d_out;

    char* base = (char*)d_ws;
    size_t off = 0;
    auto take = [&](size_t bytes) -> char* {
        char* p = base + off;
        off = (off + bytes + 255) & ~(size_t)255;
        return p;
    };
    float*    sq       = (float*)take((size_t)RR * NN * 4);
    float*    sk       = (float*)take((size_t)RR * NN * 4);
    unsigned* rowstart = (unsigned*)take((size_t)NN * 4);
    unsigned* rowdeg   = (unsigned*)take((size_t)NN * 4);
    unsigned* bcnt     = (unsigned*)take((size_t)NBKT * 4);
    unsigned* tmp      = (unsigned*)take((size_t)NBKT * CAP * 4);
    unsigned* pk       = (unsigned*)take((size_t)NBKT * CAP * 4);
    unsigned short* x1 = (unsigned short*)take((size_t)NN * 64 * 2);
    float*    stats    = (float*)take(512);
    float*    gmax     = (float*)take((size_t)NB_NODES * 8 * 4);
    float*    mxk1     = (float*)take(RR * 4);
    float*    mxk2     = (float*)take(RR * 4);
    unsigned short* Wf1 = (unsigned short*)take((size_t)RR * 128 * 64 * 2);
    unsigned short* Wf2 = (unsigned short*)take((size_t)RR * 64 * 64 * 2);
    unsigned short* Sf1 = (unsigned short*)take((size_t)128 * 16 * 2);
    unsigned short* Sf2 = (unsigned short*)take((size_t)64 * 16 * 2);
    unsigned short* xw  = (unsigned short*)take((size_t)RR * NN * 64 * 2);

    const int nb_part  = (EE + ACHUNK - 1) / ACHUNK;   // 782
    const int nb_agg   = NN / 4;                       // 25000
    const int nb_elem  = (NN * 64) / 256;

    prep<<<53, 256, 0, stream>>>(W1, q1, k1, W2, q2, k2, Wf1, Wf2, Sf1, Sf2,
                                 bcnt, stats);
    part_scatter<<<nb_part, 256, 0, stream>>>(src, dst, et, bcnt, tmp);
    bucket_csr<<<NBKT, 256, 0, stream>>>(bcnt, tmp, rowstart, rowdeg, pk);

    gemm_mfma<128, false><<<NB_NODES, 256, 0, stream>>>(x0, Wf1, Sf1, xw, sq, sk, gmax);
    max_reduce<<<1, 256, 0, stream>>>(gmax, mxk1);
    node_aggregate<1><<<nb_agg, 256, 0, stream>>>(rowstart, rowdeg, pk, sq, sk, mxk1,
                                                  xw, b1, x1);

    gemm_mfma<64, true><<<NB_NODES, 256, 0, stream>>>(x1, Wf2, Sf2, xw, sq, sk, gmax);
    max_reduce<<<1, 256, 0, stream>>>(gmax, mxk2);
    node_aggregate<2><<<nb_agg, 256, 0, stream>>>(rowstart, rowdeg, pk, sq, sk, mxk2,
                                                  xw, nullptr, out);

    bn_stats<<<512, 256, 0, stream>>>(out, stats);
    bn_apply<<<nb_elem, 256, 0, stream>>>(out, stats, gamma, beta);
}

// Round 10
// 397.802 us; speedup vs baseline: 1.2833x; 1.0420x over previous
//
#include <hip/hip_runtime.h>
#include <hip/hip_bf16.h>

#define NN 100000
#define EE 1600000
#define RR 8
#define NBKT 391          // ceil(NN/256) buckets of 256 nodes
#define ACHUNK 2048       // edges per partition block (782 blocks)
#define CAP 5120          // per-bucket capacity: mean 4096, sd ~64 -> 16 sigma headroom
#define NB_NODES ((NN + 63) / 64)   // 1563 node tiles
#define NB_PART ((EE + ACHUNK - 1) / ACHUNK)   // 782

typedef __attribute__((ext_vector_type(8))) short bf16x8;
typedef __attribute__((ext_vector_type(4))) float f32x4;

__device__ __forceinline__ unsigned short f2bf(float v) {
    __hip_bfloat16 h = __float2bfloat16(v);
    return *reinterpret_cast<unsigned short*>(&h);
}
__device__ __forceinline__ float bf2f(unsigned short u) {
    unsigned x = (unsigned)u << 16;
    return __uint_as_float(x);
}

// ---------- prep device helpers ----------
template<int IN_DIM>
__device__ __forceinline__ void wt_frag_dev(const float* __restrict__ W,
                                            unsigned short* __restrict__ Wf,
                                            int r, int blk, int nb) {
    constexpr int KSTEPS = IN_DIM / 32;
    for (int i = blk * 256 + threadIdx.x; i < IN_DIM * 64; i += nb * 256) {
        int k = i >> 6, o = i & 63;
        int ks = k >> 5, quad = (k >> 3) & 3, j = k & 7;
        int tl = o >> 4, l16 = o & 15;
        int lane = quad * 16 + l16;
        size_t idx = ((((size_t)r * KSTEPS + ks) * 4 + tl) * 64 + lane) * 8 + j;
        Wf[idx] = f2bf(W[((size_t)r * IN_DIM + k) * 64 + o]);
    }
}

template<int IN_DIM>
__device__ __forceinline__ void wqk_frag_dev(const float* __restrict__ W,
        const float* __restrict__ q, const float* __restrict__ k,
        unsigned short* __restrict__ Sf, int blk, int nb) {
    for (int i = blk * 256 + threadIdx.x; i < IN_DIM * 16; i += nb * 256) {
        int j = i & 7, lane = (i >> 3) & 63, ks = i >> 9;
        int col = lane & 15, quad = lane >> 4;
        int kd = ks * 32 + quad * 8 + j;
        const float* v = (col < 8) ? q : k;
        int r = (col < 8) ? col : col - 8;
        float s = 0.f;
        #pragma unroll
        for (int o = 0; o < 64; o++) s += W[((size_t)r * IN_DIM + kd) * 64 + o] * v[o];
        Sf[i] = f2bf(s);
    }
}

// ---------- K1: weight prep + edge partition scatter, fused at grid level ----------
// Blocks [0, NB_PART): part_scatter (independent of prep). Blocks [NB_PART, +53): prep.
// bcnt zeroed by hipMemsetAsync before this kernel.
__global__ __launch_bounds__(256)
void prep_scatter(const float* __restrict__ W1, const float* __restrict__ q1,
                  const float* __restrict__ k1,
                  const float* __restrict__ W2, const float* __restrict__ q2,
                  const float* __restrict__ k2,
                  unsigned short* __restrict__ Wf1, unsigned short* __restrict__ Wf2,
                  unsigned short* __restrict__ Sf1, unsigned short* __restrict__ Sf2,
                  float* __restrict__ stats,
                  const int* __restrict__ src, const int* __restrict__ dst,
                  const int* __restrict__ et,
                  unsigned* __restrict__ bcnt, unsigned* __restrict__ tmp)
{
    __shared__ unsigned h[NBKT], base[NBKT];
    int bb = blockIdx.x;
    if (bb < NB_PART) {
        int t = threadIdx.x;
        for (int i = t; i < NBKT; i += 256) h[i] = 0;
        __syncthreads();
        int e0 = bb * ACHUNK;
        for (int i = t; i < ACHUNK; i += 256) {
            int e = e0 + i;
            if (e < EE) atomicAdd(&h[((unsigned)dst[e]) >> 8], 1u);
        }
        __syncthreads();
        for (int i = t; i < NBKT; i += 256) {
            base[i] = (unsigned)i * CAP + (h[i] ? atomicAdd(&bcnt[i], h[i]) : 0u);
            h[i] = 0;
        }
        __syncthreads();
        for (int i = t; i < ACHUNK; i += 256) {
            int e = e0 + i;
            if (e < EE) {
                unsigned d = (unsigned)dst[e];
                unsigned bk = d >> 8;
                unsigned off = atomicAdd(&h[bk], 1u);
                unsigned pos = base[bk] + off;
                if (pos < (bk + 1u) * CAP) {   // statistically unreachable clamp (16 sigma)
                    unsigned val = ((d & 255u) << 23) | ((unsigned)et[e] << 20) | (unsigned)src[e];
                    tmp[pos] = val;
                }
            }
        }
        return;
    }
    int b = bb - NB_PART;
    if (b < 16)       wt_frag_dev<128>(W1, Wf1, b >> 1, b & 1, 2);
    else if (b < 32)  wt_frag_dev<64>(W2, Wf2, (b - 16) >> 1, b & 1, 2);
    else if (b < 48)  wqk_frag_dev<128>(W1, q1, k1, Sf1, b - 32, 16);
    else if (b < 52)  wqk_frag_dev<64>(W2, q2, k2, Sf2, b - 48, 4);
    else {
        int t = threadIdx.x;
        if (t < 128) stats[t] = 0.f;
    }
}

// ---------- bucket CSR body (device fn; runs as prologue blocks of gemm_csr) ----------
__device__ __forceinline__ void bucket_csr_body(const unsigned* __restrict__ bcnt,
        const unsigned* __restrict__ tmp, unsigned* __restrict__ rowstart,
        unsigned* __restrict__ rowdeg, unsigned* __restrict__ pk, int b)
{
    __shared__ unsigned lcnt[256], lscan[256], lrs[256];
    int t = threadIdx.x;
    unsigned ebeg = (unsigned)b * CAP;
    unsigned cnt = min(bcnt[b], (unsigned)CAP);
    unsigned eend = ebeg + cnt;
    lcnt[t] = 0;
    __syncthreads();
    for (unsigned i = ebeg + t; i < eend; i += 256)
        atomicAdd(&lcnt[tmp[i] >> 23], 1u);
    __syncthreads();
    unsigned v = lcnt[t];
    lscan[t] = v;
    __syncthreads();
    for (int off = 1; off < 256; off <<= 1) {
        unsigned u = (t >= off) ? lscan[t - off] : 0u;
        __syncthreads();
        lscan[t] += u;
        __syncthreads();
    }
    unsigned excl = lscan[t] - v;
    lrs[t] = ebeg + excl;
    int node = b * 256 + t;
    if (node < NN) { rowstart[node] = ebeg + excl; rowdeg[node] = v; }
    lcnt[t] = 0;
    __syncthreads();
    for (unsigned i = ebeg + t; i < eend; i += 256) {
        unsigned val = tmp[i];
        unsigned d = val >> 23;
        unsigned pos = lrs[d] + atomicAdd(&lcnt[d], 1u);
        pk[pos] = val & 0x7FFFFFu;
    }
}

// ---------- K2: MFMA GEMM (R5/R6-proven serial-relation form) ∪ bucket_csr ----------
// with_csr=1: blocks [0,NBKT) build the CSR (independent of the gemm; both deps
// satisfied by K1) while gemm blocks — 84% stall-bound (R3-R8, 5 variants) —
// run alongside. The csr work hides in the gemm's idle cycles.
// Do not restructure the gemm again without new counter evidence
// (dbuf R7: occupancy cliff; grid-parallel relations R8: FETCH 26->201MB).
template<int IN_DIM, bool BF16IN>
__global__ __launch_bounds__(256)
void gemm_csr(const void* __restrict__ xv, const unsigned short* __restrict__ Wf,
              const unsigned short* __restrict__ Sf,
              unsigned short* __restrict__ xw,
              float* __restrict__ sq, float* __restrict__ sk,
              float* __restrict__ gmax,
              const unsigned* __restrict__ bcnt, const unsigned* __restrict__ tmp,
              unsigned* __restrict__ rowstart, unsigned* __restrict__ rowdeg,
              unsigned* __restrict__ pk, int with_csr)
{
    constexpr int KSTEPS = IN_DIM / 32;
    constexpr int NB = IN_DIM / 8;
    constexpr int WITEMS = KSTEPS * 4 * 64;           // bf16x8 items per relation
    __shared__ alignas(16) unsigned short xl[64 * IN_DIM];
    __shared__ alignas(16) unsigned short wl[WITEMS * 8];   // 16KB (128) / 8KB (64)
    __shared__ float smax[4][8];

    if (with_csr && blockIdx.x < NBKT) {
        bucket_csr_body(bcnt, tmp, rowstart, rowdeg, pk, blockIdx.x);
        return;
    }
    const int nblk = blockIdx.x - (with_csr ? NBKT : 0);

    const int n0 = nblk * 64;
    const int t = threadIdx.x;
    const int wave = t >> 6, lane = t & 63;
    const int quad = lane >> 4, l16 = lane & 15;

    for (int c = t; c < 64 * IN_DIM / 4; c += 256) {
        int row = c / (IN_DIM / 4), kc = (c % (IN_DIM / 4)) * 4;
        int gr = n0 + row;
        ushort4 u = make_ushort4(0, 0, 0, 0);
        if constexpr (BF16IN) {
            if (gr < NN) u = *(const ushort4*)((const unsigned short*)xv + (size_t)gr * IN_DIM + kc);
        } else {
            if (gr < NN) {
                float4 v = *(const float4*)((const float*)xv + (size_t)gr * IN_DIM + kc);
                u.x = f2bf(v.x); u.y = f2bf(v.y); u.z = f2bf(v.z); u.w = f2bf(v.w);
            }
        }
        int b = kc >> 3;
        *(ushort4*)&xl[row * IN_DIM + ((b ^ (row & (NB - 1))) << 3) + (kc & 7)] = u;
    }
    __syncthreads();

    bf16x8 afr[KSTEPS];
    const int arow = wave * 16 + l16;
    #pragma unroll
    for (int ks = 0; ks < KSTEPS; ks++) {
        int b = ks * 4 + quad;
        afr[ks] = *(const bf16x8*)&xl[arow * IN_DIM + ((b ^ (arow & (NB - 1))) << 3)];
    }

    // ---- sq/sk for ALL relations via one MFMA chain + per-block sk max ----
    {
        f32x4 accs = {0.f, 0.f, 0.f, 0.f};
        #pragma unroll
        for (int ks = 0; ks < KSTEPS; ks++) {
            bf16x8 sfr = *(const bf16x8*)&Sf[(ks * 64 + lane) * 8];
            accs = __builtin_amdgcn_mfma_f32_16x16x32_bf16(afr[ks], sfr, accs, 0, 0, 0);
        }
        float pm = -1e30f;
        #pragma unroll
        for (int reg = 0; reg < 4; reg++) {
            int grow = n0 + wave * 16 + quad * 4 + reg;
            if (grow < NN) {
                if (l16 < 8) sq[(size_t)l16 * NN + grow] = accs[reg];
                else { sk[(size_t)(l16 - 8) * NN + grow] = accs[reg]; pm = fmaxf(pm, accs[reg]); }
            }
        }
        pm = fmaxf(pm, __shfl_xor(pm, 16, 64));
        pm = fmaxf(pm, __shfl_xor(pm, 32, 64));
        if (quad == 0 && l16 >= 8) smax[wave][l16 - 8] = pm;
    }
    __syncthreads();
    if (t < 8) {
        float v = fmaxf(fmaxf(smax[0][t], smax[1][t]), fmaxf(smax[2][t], smax[3][t]));
        gmax[nblk * 8 + t] = v;                       // plain store, no RMW
    }

    #pragma unroll 1
    for (int r = 0; r < RR; r++) {
        // cooperative staging: 256 threads, coalesced 16B loads, deeply pipelined
        const unsigned short* Wr = Wf + (size_t)r * WITEMS * 8;
        #pragma unroll
        for (int i = t; i < WITEMS; i += 256)
            *(bf16x8*)&wl[(size_t)i * 8] = *(const bf16x8*)(Wr + (size_t)i * 8);
        __syncthreads();

        bf16x8 bfr[KSTEPS][4];
        #pragma unroll
        for (int ks = 0; ks < KSTEPS; ks++)
            #pragma unroll
            for (int tl = 0; tl < 4; tl++)
                bfr[ks][tl] = *(const bf16x8*)&wl[(size_t)((ks * 4 + tl) * 64 + lane) * 8];

        f32x4 acc[4] = {{0.f,0.f,0.f,0.f},{0.f,0.f,0.f,0.f},{0.f,0.f,0.f,0.f},{0.f,0.f,0.f,0.f}};
        #pragma unroll
        for (int ks = 0; ks < KSTEPS; ks++)
            #pragma unroll
            for (int tl = 0; tl < 4; tl++)
                acc[tl] = __builtin_amdgcn_mfma_f32_16x16x32_bf16(afr[ks], bfr[ks][tl], acc[tl], 0, 0, 0);

        const size_t rbase = (size_t)r * NN;
        #pragma unroll
        for (int reg = 0; reg < 4; reg++) {
            int grow = n0 + wave * 16 + quad * 4 + reg;
            if (grow < NN) {
                ushort4 u;
                u.x = f2bf(acc[0][reg]); u.y = f2bf(acc[1][reg]);
                u.z = f2bf(acc[2][reg]); u.w = f2bf(acc[3][reg]);
                *(ushort4*)(xw + (rbase + grow) * 64 + l16 * 4) = u;
            }
        }
        __syncthreads();   // wl reads done before next relation's staging
    }
}

// ---------- parallel tree-reduce: gmax[1563][8] -> mxk[8] (R5-proven) ----------
__global__ __launch_bounds__(256)
void max_reduce(const float* __restrict__ gmax, float* __restrict__ mxk) {
    __shared__ float smr[32][8];
    int t = threadIdx.x;
    int r = t & 7, grp = t >> 3;                      // 32 groups of 8
    float m0 = -1e30f, m1 = -1e30f, m2 = -1e30f, m3 = -1e30f;
    for (int i = grp; i < NB_NODES; i += 128) {
        m0 = fmaxf(m0, gmax[i * 8 + r]);
        int i1 = i + 32, i2 = i + 64, i3 = i + 96;
        if (i1 < NB_NODES) m1 = fmaxf(m1, gmax[i1 * 8 + r]);
        if (i2 < NB_NODES) m2 = fmaxf(m2, gmax[i2 * 8 + r]);
        if (i3 < NB_NODES) m3 = fmaxf(m3, gmax[i3 * 8 + r]);
    }
    smr[grp][r] = fmaxf(fmaxf(m0, m1), fmaxf(m2, m3));
    __syncthreads();
    if (t < 8) {
        float mm = smr[0][t];
        #pragma unroll
        for (int g2 = 1; g2 < 32; g2++) mm = fmaxf(mm, smr[g2][t]);
        mxk[t] = mm;
    }
}

// ---------- Fused per-node softmax + aggregate (R5/R9-proven form, 57.4us) ----------
// 4 groups of 16 lanes, 8 edges / 2 independent 8B gathers in flight.
// At the random-gather BW ceiling (~3.3 TB/s; R5/R6 nulls) — treat as floor.
template<int LAYER>
__global__ __launch_bounds__(256)
void node_aggregate(const unsigned* __restrict__ rowstart, const unsigned* __restrict__ rowdeg,
                    const unsigned* __restrict__ pk,
                    const float* __restrict__ sq, const float* __restrict__ sk,
                    const float* __restrict__ mxk,
                    const unsigned short* __restrict__ xw, const float* __restrict__ b,
                    void* __restrict__ outv)
{
    const int node = blockIdx.x * 4 + (threadIdx.x >> 6);
    const int lane = threadIdx.x & 63;
    const int g = lane >> 4, c16 = lane & 15;
    const unsigned beg = rowstart[node];
    const unsigned deg = rowdeg[node];
    const unsigned end = beg + deg;

    const float sqreg = sq[(size_t)(lane & 7) * NN + node];
    float tmx = sqreg + mxk[lane & 7];
    tmx = fmaxf(tmx, __shfl_xor(tmx, 1, 64));
    tmx = fmaxf(tmx, __shfl_xor(tmx, 2, 64));
    tmx = fmaxf(tmx, __shfl_xor(tmx, 4, 64));
    const float m = tmx > 0.f ? tmx : 0.2f * tmx;   // leaky is monotonic: bound survives

    float a0 = 0.f, a1 = 0.f, a2 = 0.f, a3 = 0.f, den = 0.f;
    for (unsigned c0 = beg; c0 < end; c0 += 64) {
        unsigned i = c0 + lane;
        unsigned p = 0;
        if (i < end) p = pk[i];
        unsigned r = p >> 20;
        unsigned rowidx = r * NN + (p & 0xFFFFFu);   // pads -> row 0 (harmless)
        float skv = sk[rowidx];
        float sqv_e = __shfl(sqreg, (int)r, 64);     // uniform flow: sources active
        float a = sqv_e + skv;
        a = a > 0.f ? a : 0.2f * a;
        float w = __expf(a - m);
        if (i >= end) w = 0.f;
        den += w;
        int cnt8 = ((int)min(64u, end - c0) + 7) & ~7;   // pad lanes have w=0
        for (int j = 0; j < cnt8; j += 8) {
            float    w0 = __shfl(w, j + g, 64);
            unsigned r0 = (unsigned)__shfl((int)rowidx, j + g, 64);
            float    w1 = __shfl(w, j + 4 + g, 64);
            unsigned r1 = (unsigned)__shfl((int)rowidx, j + 4 + g, 64);
            ushort4 v0 = *(const ushort4*)(xw + (size_t)r0 * 64 + c16 * 4);
            ushort4 v1 = *(const ushort4*)(xw + (size_t)r1 * 64 + c16 * 4);
            a0 += w0 * bf2f(v0.x) + w1 * bf2f(v1.x);
            a1 += w0 * bf2f(v0.y) + w1 * bf2f(v1.y);
            a2 += w0 * bf2f(v0.z) + w1 * bf2f(v1.z);
            a3 += w0 * bf2f(v0.w) + w1 * bf2f(v1.w);
        }
    }
    #pragma unroll
    for (int off = 32; off >= 1; off >>= 1)
        den += __shfl_xor(den, off, 64);
    // combine the 4 edge-subgroups: lanes L, L^16, L^32, L^48 hold same channels
    a0 += __shfl_xor(a0, 16, 64); a0 += __shfl_xor(a0, 32, 64);
    a1 += __shfl_xor(a1, 16, 64); a1 += __shfl_xor(a1, 32, 64);
    a2 += __shfl_xor(a2, 16, 64); a2 += __shfl_xor(a2, 32, 64);
    a3 += __shfl_xor(a3, 16, 64); a3 += __shfl_xor(a3, 32, 64);

    float accg = (g == 0) ? a0 : (g == 1) ? a1 : (g == 2) ? a2 : a3;
    float res = (deg > 0) ? accg / (den + 1e-16f) : 0.f;
    int c = g * 16 + c16;
    if constexpr (LAYER == 1) {
        res += b[c];
        res = res > 0.f ? res : 0.f;
        ((unsigned short*)outv)[(size_t)node * 64 + c] = f2bf(res);
    } else {
        ((float*)outv)[(size_t)node * 64 + c] = res;
    }
}

// ---------------- BatchNorm (separate stats kernel: 512 blocks -> 65k atomics, R0-proven) ----
__global__ __launch_bounds__(256)
void bn_stats(const float* __restrict__ x, float* __restrict__ stats)
{
    int c = threadIdx.x & 63;
    int w = threadIdx.x >> 6;
    float s = 0.f, s2 = 0.f;
    for (int row = blockIdx.x * 4 + w; row < NN; row += gridDim.x * 4) {
        float v = x[(size_t)row * 64 + c];
        s += v; s2 += v * v;
    }
    __shared__ float ls[4][64], ls2[4][64];
    ls[w][c] = s; ls2[w][c] = s2;
    __syncthreads();
    if (threadIdx.x < 64) {
        atomicAdd(&stats[c],      ls[0][c] + ls[1][c] + ls[2][c] + ls[3][c]);
        atomicAdd(&stats[64 + c], ls2[0][c] + ls2[1][c] + ls2[2][c] + ls2[3][c]);
    }
}

__global__ __launch_bounds__(256)
void bn_apply(float* __restrict__ x, const float* __restrict__ stats,
              const float* __restrict__ gamma, const float* __restrict__ beta)
{
    int i = blockIdx.x * 256 + threadIdx.x;
    if (i >= NN * 64) return;
    int c = i & 63;
    float mean = stats[c] * (1.f / NN);
    float var  = stats[64 + c] * (1.f / NN) - mean * mean;
    float sc   = rsqrtf(var + 1e-5f) * gamma[c];
    float v = (x[i] - mean) * sc + beta[c];
    x[i] = v > 0.f ? v : 0.01f * v;
}

// ---------------- driver ----------------
extern "C" void kernel_launch(void* const* d_in, const int* in_sizes, int n_in,
                              void* d_out, int out_size, void* d_ws, size_t ws_size,
                              hipStream_t stream)
{
    const float* x0 = (const float*)d_in[0];
    const int*   ei = (const int*)d_in[1];
    const int*   et = (const int*)d_in[2];
    const float* W1 = (const float*)d_in[3];
    const float* q1 = (const float*)d_in[4];
    const float* k1 = (const float*)d_in[5];
    const float* b1 = (const float*)d_in[6];
    const float* W2 = (const float*)d_in[7];
    const float* q2 = (const float*)d_in[8];
    const float* k2 = (const float*)d_in[9];
    const float* gamma = (const float*)d_in[11];
    const float* beta  = (const float*)d_in[12];
    const int* src = ei;
    const int* dst = ei + EE;
    float* out = (float*)d_out;

    char* base = (char*)d_ws;
    size_t off = 0;
    auto take = [&](size_t bytes) -> char* {
        char* p = base + off;
        off = (off + bytes + 255) & ~(size_t)255;
        return p;
    };
    float*    sq       = (float*)take((size_t)RR * NN * 4);
    float*    sk       = (float*)take((size_t)RR * NN * 4);
    unsigned* rowstart = (unsigned*)take((size_t)NN * 4);
    unsigned* rowdeg   = (unsigned*)take((size_t)NN * 4);
    unsigned* bcnt     = (unsigned*)take((size_t)NBKT * 4);
    unsigned* tmp      = (unsigned*)take((size_t)NBKT * CAP * 4);
    unsigned* pk       = (unsigned*)take((size_t)NBKT * CAP * 4);
    unsigned short* x1 = (unsigned short*)take((size_t)NN * 64 * 2);
    float*    stats    = (float*)take(512);
    float*    gmax     = (float*)take((size_t)NB_NODES * 8 * 4);
    float*    mxk1     = (float*)take(RR * 4);
    float*    mxk2     = (float*)take(RR * 4);
    unsigned short* Wf1 = (unsigned short*)take((size_t)RR * 128 * 64 * 2);
    unsigned short* Wf2 = (unsigned short*)take((size_t)RR * 64 * 64 * 2);
    unsigned short* Sf1 = (unsigned short*)take((size_t)128 * 16 * 2);
    unsigned short* Sf2 = (unsigned short*)take((size_t)64 * 16 * 2);
    unsigned short* xw  = (unsigned short*)take((size_t)RR * NN * 64 * 2);

    const int nb_agg   = NN / 4;                       // 25000
    const int nb_elem  = (NN * 64) / 256;

    hipMemsetAsync(bcnt, 0, (size_t)NBKT * 4, stream);
    prep_scatter<<<NB_PART + 53, 256, 0, stream>>>(W1, q1, k1, W2, q2, k2,
                                                   Wf1, Wf2, Sf1, Sf2, stats,
                                                   src, dst, et, bcnt, tmp);

    gemm_csr<128, false><<<NBKT + NB_NODES, 256, 0, stream>>>(
        x0, Wf1, Sf1, xw, sq, sk, gmax, bcnt, tmp, rowstart, rowdeg, pk, 1);
    max_reduce<<<1, 256, 0, stream>>>(gmax, mxk1);
    node_aggregate<1><<<nb_agg, 256, 0, stream>>>(rowstart, rowdeg, pk, sq, sk, mxk1,
                                                  xw, b1, x1);

    gemm_csr<64, true><<<NB_NODES, 256, 0, stream>>>(
        x1, Wf2, Sf2, xw, sq, sk, gmax, bcnt, tmp, rowstart, rowdeg, pk, 0);
    max_reduce<<<1, 256, 0, stream>>>(gmax, mxk2);
    node_aggregate<2><<<nb_agg, 256, 0, stream>>>(rowstart, rowdeg, pk, sq, sk, mxk2,
                                                  xw, nullptr, out);

    bn_stats<<<512, 256, 0, stream>>>(out, stats);
    bn_apply<<<nb_elem, 256, 0, stream>>>(out, stats, gamma, beta);
}